// Round 1
// baseline (11570.670 us; speedup 1.0000x reference)
//
#include <hip/hip_runtime.h>
#include <math.h>

#define BM 64
#define BK 32
#define LDT 68  // BM + 4 pad: keeps float4 reads 16B-aligned (68*4=272, 272%16==0)

// Generic tiled f32 GEMM: out[M,Ncols] = ep(A[M,K] @ W[K,Ncols] + bias)
// Block computes BM rows x 128 cols. Epilogue options:
//   TANH : v = tanhf(v)
//   RESID: v += resid[row] (after tanh)  [lft/rgt tower residual]
//   L2   : row-wise l2 normalize (needs Ncols==128, full row in block)
//   AUX  : aux_out[row] = aux_in[row] + v (after everything)  [gnn_acc]
template<bool TANH, bool L2, bool RESID, bool AUX>
__global__ __launch_bounds__(256)
void gemm_ep(const float* __restrict__ A, const float* __restrict__ W,
             const float* __restrict__ bias, const float* __restrict__ resid,
             const float* __restrict__ aux_in, float* __restrict__ aux_out,
             float* __restrict__ out, int M, int K, int Ncols)
{
    __shared__ __align__(16) float As[BK][LDT];   // transposed A tile
    __shared__ __align__(16) float Ws[BK][128];

    const int tid  = threadIdx.x;
    const int row0 = blockIdx.x * BM;
    const int col0 = blockIdx.y * 128;
    const int cg   = tid & 31;   // column group: cols col0 + cg*4 .. +3
    const int rg   = tid >> 5;   // row group: rows row0 + rg*8 .. +7

    float acc[8][4];
#pragma unroll
    for (int i = 0; i < 8; i++)
#pragma unroll
        for (int j = 0; j < 4; j++) acc[i][j] = 0.f;

    for (int k0 = 0; k0 < K; k0 += BK) {
        // stage A tile (transposed): 512 float4 loads, 2 per thread
#pragma unroll
        for (int jj = 0; jj < 2; jj++) {
            int f  = jj * 256 + tid;        // 0..511
            int r  = f >> 3;
            int c4 = (f & 7) << 2;
            float4 a = make_float4(0.f, 0.f, 0.f, 0.f);
            int row = row0 + r;
            if (row < M) a = *(const float4*)(A + (size_t)row * K + k0 + c4);
            As[c4 + 0][r] = a.x; As[c4 + 1][r] = a.y;
            As[c4 + 2][r] = a.z; As[c4 + 3][r] = a.w;
        }
        // stage W tile: 1024 float4 loads, 4 per thread
#pragma unroll
        for (int jj = 0; jj < 4; jj++) {
            int f  = jj * 256 + tid;        // 0..1023
            int k  = f >> 5;
            int c4 = (f & 31) << 2;
            *(float4*)&Ws[k][c4] = *(const float4*)(W + (size_t)(k0 + k) * Ncols + col0 + c4);
        }
        __syncthreads();
#pragma unroll
        for (int k = 0; k < BK; k++) {
            float4 a0 = *(const float4*)&As[k][rg * 8];
            float4 a1 = *(const float4*)&As[k][rg * 8 + 4];
            float4 w  = *(const float4*)&Ws[k][cg * 4];
            float av[8] = {a0.x, a0.y, a0.z, a0.w, a1.x, a1.y, a1.z, a1.w};
#pragma unroll
            for (int i = 0; i < 8; i++) {
                acc[i][0] += av[i] * w.x;
                acc[i][1] += av[i] * w.y;
                acc[i][2] += av[i] * w.z;
                acc[i][3] += av[i] * w.w;
            }
        }
        __syncthreads();
    }

    // epilogue
    float bv[4] = {0.f, 0.f, 0.f, 0.f};
    if (bias) {
        float4 b4 = *(const float4*)(bias + col0 + cg * 4);
        bv[0] = b4.x; bv[1] = b4.y; bv[2] = b4.z; bv[3] = b4.w;
    }
#pragma unroll
    for (int i = 0; i < 8; i++) {
        int row = row0 + rg * 8 + i;
        if (row >= M) continue;   // uniform within each 32-lane group -> shfl safe
        float v[4];
#pragma unroll
        for (int j = 0; j < 4; j++) v[j] = acc[i][j] + bv[j];
        if (TANH) {
#pragma unroll
            for (int j = 0; j < 4; j++) v[j] = tanhf(v[j]);
        }
        if (RESID) {
            float4 rr = *(const float4*)(resid + (size_t)row * Ncols + col0 + cg * 4);
            v[0] += rr.x; v[1] += rr.y; v[2] += rr.z; v[3] += rr.w;
        }
        if (L2) {
            float s = v[0]*v[0] + v[1]*v[1] + v[2]*v[2] + v[3]*v[3];
#pragma unroll
            for (int m = 16; m >= 1; m >>= 1) s += __shfl_xor(s, m);
            float sc = 1.f / fmaxf(sqrtf(s), 1e-12f);
#pragma unroll
            for (int j = 0; j < 4; j++) v[j] *= sc;
        }
        float4 o = make_float4(v[0], v[1], v[2], v[3]);
        *(float4*)(out + (size_t)row * Ncols + col0 + cg * 4) = o;
        if (AUX) {
            float4 ai = *(const float4*)(aux_in + (size_t)row * Ncols + col0 + cg * 4);
            float4 ao = make_float4(ai.x + o.x, ai.y + o.y, ai.z + o.z, ai.w + o.w);
            *(float4*)(aux_out + (size_t)row * Ncols + col0 + cg * 4) = ao;
        }
    }
}

// SpMM scatter: h[rows[e]] += vals[e] * emb[cols[e]], D=128.
// 32 threads per edge, each does a float4 gather + 4 atomic adds.
__global__ __launch_bounds__(256)
void spmm_scatter(const int* __restrict__ rows, const int* __restrict__ cols,
                  const float* __restrict__ vals, const float* __restrict__ emb,
                  float* __restrict__ h, int E)
{
    int gid = blockIdx.x * 256 + threadIdx.x;
    int e = gid >> 5;
    if (e >= E) return;
    int l = gid & 31;
    int c = cols[e];
    int r = rows[e];
    float v = vals[e];
    float4 m = *(const float4*)(emb + (size_t)c * 128 + l * 4);
    float* o = h + (size_t)r * 128 + l * 4;
    atomicAdd(o + 0, v * m.x);
    atomicAdd(o + 1, v * m.y);
    atomicAdd(o + 2, v * m.z);
    atomicAdd(o + 3, v * m.w);
}

extern "C" void kernel_launch(void* const* d_in, const int* in_sizes, int n_in,
                              void* d_out, int out_size, void* d_ws, size_t ws_size,
                              hipStream_t stream)
{
    const float* feat  = (const float*)d_in[0];
    const int*   srows = (const int*)  d_in[1];
    const int*   scols = (const int*)  d_in[2];
    const float* svals = (const float*)d_in[3];
    const float* Wf0   = (const float*)d_in[4];
    const float* bf0   = (const float*)d_in[5];
    const float* Wf1   = (const float*)d_in[6];
    const float* bf1   = (const float*)d_in[7];
    const float* Wg    = (const float*)d_in[8];
    const float* Wemb  = (const float*)d_in[9];
    const float* bemb  = (const float*)d_in[10];
    const float* Wl    = (const float*)d_in[11];
    const float* bl    = (const float*)d_in[12];
    const float* Wr    = (const float*)d_in[13];
    const float* br    = (const float*)d_in[14];

    const int M = in_sizes[0] / 512;   // 100000
    const int E = in_sizes[1];         // 3200000

    float* out  = (float*)d_out;
    float* embO = out;
    float* lftO = out + (size_t)M * 128;
    float* rgtO = out + (size_t)M * 256;

    float* ws = (float*)d_ws;
    float* x  = ws;                        // [M,128]
    float* h  = ws + (size_t)M * 128;      // [M,128] spmm accumulator
    float* x1 = out;                       // [M,256] scratch in d_out (emb+lft regions, dead before final writes)
    float* n0 = rgtO;                      // [M,128] scratch in rgt region (dead before step 10)
    float* n1 = x;                         // reuse x after it's consumed
    float* acc = embO;                     // gnn_acc lives in emb region, finished in-place

    dim3 blk(256);
    const int gm = (M + BM - 1) / BM;

    // 1. x1 = tanh(feat @ Wf0 + bf0)                     [M,512]->[M,256]
    gemm_ep<true,false,false,false><<<dim3(gm,2),blk,0,stream>>>(feat,Wf0,bf0,nullptr,nullptr,nullptr,x1,M,512,256);
    // 2. x = tanh(x1 @ Wf1 + bf1)                        [M,256]->[M,128]
    gemm_ep<true,false,false,false><<<dim3(gm,1),blk,0,stream>>>(x1,Wf1,bf1,nullptr,nullptr,nullptr,x,M,256,128);
    // 3. h = spmm(x)
    hipMemsetAsync(h, 0, (size_t)M * 128 * 4, stream);
    const int sgrid = (int)(((long long)E * 32 + 255) / 256);
    spmm_scatter<<<sgrid,blk,0,stream>>>(srows,scols,svals,x,h,E);
    // 4. n0 = l2norm(tanh(h @ Wg0)); acc = x + n0
    gemm_ep<true,true,false,true><<<dim3(gm,1),blk,0,stream>>>(h,Wg,nullptr,nullptr,x,acc,n0,M,128,128);
    // 5. h = spmm(n0)
    hipMemsetAsync(h, 0, (size_t)M * 128 * 4, stream);
    spmm_scatter<<<sgrid,blk,0,stream>>>(srows,scols,svals,n0,h,E);
    // 6. n1 = l2norm(tanh(h @ Wg1)); acc += n1
    gemm_ep<true,true,false,true><<<dim3(gm,1),blk,0,stream>>>(h,Wg+128*128,nullptr,nullptr,acc,acc,n1,M,128,128);
    // 7. emb = l2norm(acc @ Wemb + bemb)   (in-place over acc)
    gemm_ep<false,true,false,false><<<dim3(gm,1),blk,0,stream>>>(acc,Wemb,bemb,nullptr,nullptr,nullptr,embO,M,128,128);
    // 8. lft0 = tanh(n1 @ Wl0 + bl0) + n1
    gemm_ep<true,false,true,false><<<dim3(gm,1),blk,0,stream>>>(n1,Wl,bl,n1,nullptr,nullptr,lftO,M,128,128);
    // 9. lft = tanh(lft0 @ Wl1 + bl1)      (in-place)
    gemm_ep<true,false,false,false><<<dim3(gm,1),blk,0,stream>>>(lftO,Wl+128*128,bl+128,nullptr,nullptr,nullptr,lftO,M,128,128);
    // 10. rgt0 = tanh(n1 @ Wr0 + br0) + n1
    gemm_ep<true,false,true,false><<<dim3(gm,1),blk,0,stream>>>(n1,Wr,br,n1,nullptr,nullptr,rgtO,M,128,128);
    // 11. rgt = tanh(rgt0 @ Wr1 + br1)     (in-place)
    gemm_ep<true,false,false,false><<<dim3(gm,1),blk,0,stream>>>(rgtO,Wr+128*128,br+128,nullptr,nullptr,nullptr,rgtO,M,128,128);
}

// Round 2
// 2410.766 us; speedup vs baseline: 4.7996x; 4.7996x over previous
//
#include <hip/hip_runtime.h>
#include <math.h>

#define BM 64
#define BK 32
#define LDT 68  // BM + 4 pad (68*4=272, %16==0 keeps float4 reads aligned)

// ---------------- generic tiled f32 GEMM with fused epilogue ----------------
template<bool TANH, bool L2, bool RESID, bool AUX>
__global__ __launch_bounds__(256)
void gemm_ep(const float* __restrict__ A, const float* __restrict__ W,
             const float* __restrict__ bias, const float* __restrict__ resid,
             const float* __restrict__ aux_in, float* __restrict__ aux_out,
             float* __restrict__ out, int M, int K, int Ncols)
{
    __shared__ __align__(16) float As[BK][LDT];
    __shared__ __align__(16) float Ws[BK][128];

    const int tid  = threadIdx.x;
    const int row0 = blockIdx.x * BM;
    const int col0 = blockIdx.y * 128;
    const int cg   = tid & 31;
    const int rg   = tid >> 5;

    float acc[8][4];
#pragma unroll
    for (int i = 0; i < 8; i++)
#pragma unroll
        for (int j = 0; j < 4; j++) acc[i][j] = 0.f;

    for (int k0 = 0; k0 < K; k0 += BK) {
#pragma unroll
        for (int jj = 0; jj < 2; jj++) {
            int f  = jj * 256 + tid;
            int r  = f >> 3;
            int c4 = (f & 7) << 2;
            float4 a = make_float4(0.f, 0.f, 0.f, 0.f);
            int row = row0 + r;
            if (row < M) a = *(const float4*)(A + (size_t)row * K + k0 + c4);
            As[c4 + 0][r] = a.x; As[c4 + 1][r] = a.y;
            As[c4 + 2][r] = a.z; As[c4 + 3][r] = a.w;
        }
#pragma unroll
        for (int jj = 0; jj < 4; jj++) {
            int f  = jj * 256 + tid;
            int k  = f >> 5;
            int c4 = (f & 31) << 2;
            *(float4*)&Ws[k][c4] = *(const float4*)(W + (size_t)(k0 + k) * Ncols + col0 + c4);
        }
        __syncthreads();
#pragma unroll
        for (int k = 0; k < BK; k++) {
            float4 a0 = *(const float4*)&As[k][rg * 8];
            float4 a1 = *(const float4*)&As[k][rg * 8 + 4];
            float4 w  = *(const float4*)&Ws[k][cg * 4];
            float av[8] = {a0.x, a0.y, a0.z, a0.w, a1.x, a1.y, a1.z, a1.w};
#pragma unroll
            for (int i = 0; i < 8; i++) {
                acc[i][0] += av[i] * w.x;
                acc[i][1] += av[i] * w.y;
                acc[i][2] += av[i] * w.z;
                acc[i][3] += av[i] * w.w;
            }
        }
        __syncthreads();
    }

    float bv[4] = {0.f, 0.f, 0.f, 0.f};
    if (bias) {
        float4 b4 = *(const float4*)(bias + col0 + cg * 4);
        bv[0] = b4.x; bv[1] = b4.y; bv[2] = b4.z; bv[3] = b4.w;
    }
#pragma unroll
    for (int i = 0; i < 8; i++) {
        int row = row0 + rg * 8 + i;
        if (row >= M) continue;
        float v[4];
#pragma unroll
        for (int j = 0; j < 4; j++) v[j] = acc[i][j] + bv[j];
        if (TANH) {
#pragma unroll
            for (int j = 0; j < 4; j++) v[j] = tanhf(v[j]);
        }
        if (RESID) {
            float4 rr = *(const float4*)(resid + (size_t)row * Ncols + col0 + cg * 4);
            v[0] += rr.x; v[1] += rr.y; v[2] += rr.z; v[3] += rr.w;
        }
        if (L2) {
            float s = v[0]*v[0] + v[1]*v[1] + v[2]*v[2] + v[3]*v[3];
#pragma unroll
            for (int m = 16; m >= 1; m >>= 1) s += __shfl_xor(s, m);
            float sc = 1.f / fmaxf(sqrtf(s), 1e-12f);
#pragma unroll
            for (int j = 0; j < 4; j++) v[j] *= sc;
        }
        float4 o = make_float4(v[0], v[1], v[2], v[3]);
        *(float4*)(out + (size_t)row * Ncols + col0 + cg * 4) = o;
        if (AUX) {
            float4 ai = *(const float4*)(aux_in + (size_t)row * Ncols + col0 + cg * 4);
            float4 ao = make_float4(ai.x + o.x, ai.y + o.y, ai.z + o.z, ai.w + o.w);
            *(float4*)(aux_out + (size_t)row * Ncols + col0 + cg * 4) = ao;
        }
    }
}

// ---------------- CSR build ----------------
__global__ __launch_bounds__(256)
void hist_k(const int* __restrict__ rows, int* __restrict__ cnt, int E)
{
    int e = blockIdx.x * 256 + threadIdx.x;
    if (e < E) atomicAdd(&cnt[rows[e]], 1);
}

#define SCAN_TILE 2048  // 256 thr * 8

__global__ __launch_bounds__(256)
void scan_phaseA(const int* __restrict__ cnt, int* __restrict__ tilesum, int N)
{
    __shared__ int sdata[256];
    int base = blockIdx.x * SCAN_TILE + threadIdx.x * 8;
    int s = 0;
#pragma unroll
    for (int j = 0; j < 8; j++) { int i = base + j; if (i < N) s += cnt[i]; }
    sdata[threadIdx.x] = s; __syncthreads();
    for (int off = 128; off > 0; off >>= 1) {
        if (threadIdx.x < off) sdata[threadIdx.x] += sdata[threadIdx.x + off];
        __syncthreads();
    }
    if (threadIdx.x == 0) tilesum[blockIdx.x] = sdata[0];
}

__global__ void scan_phaseB(int* __restrict__ tilesum, int* __restrict__ rowptr,
                            int numTiles, int N)
{
    if (threadIdx.x == 0 && blockIdx.x == 0) {
        int run = 0;
        for (int t = 0; t < numTiles; t++) { int v = tilesum[t]; tilesum[t] = run; run += v; }
        rowptr[N] = run;   // == E
    }
}

__global__ __launch_bounds__(256)
void scan_phaseC(const int* __restrict__ cnt, const int* __restrict__ tilesum,
                 int* __restrict__ rowptr, int N)
{
    __shared__ int sdata[256];
    int base = blockIdx.x * SCAN_TILE + threadIdx.x * 8;
    int loc[8]; int s = 0;
#pragma unroll
    for (int j = 0; j < 8; j++) {
        int i = base + j; int v = (i < N) ? cnt[i] : 0;
        loc[j] = s; s += v;
    }
    sdata[threadIdx.x] = s; __syncthreads();
    int x = s;
    for (int off = 1; off < 256; off <<= 1) {
        int t = 0;
        if (threadIdx.x >= off) t = sdata[threadIdx.x - off];
        __syncthreads();
        x += t;
        sdata[threadIdx.x] = x;
        __syncthreads();
    }
    int texcl = x - s + tilesum[blockIdx.x];
#pragma unroll
    for (int j = 0; j < 8; j++) {
        int i = base + j;
        if (i < N) rowptr[i] = texcl + loc[j];
    }
}

__global__ __launch_bounds__(256)
void reorder_k(const int* __restrict__ rows, const int* __restrict__ cols,
               const float* __restrict__ vals, const int* __restrict__ rowptr,
               int* __restrict__ cur, int2* __restrict__ packed, int E)
{
    int e = blockIdx.x * 256 + threadIdx.x;
    if (e >= E) return;
    int r = rows[e];
    int pos = rowptr[r] + atomicAdd(&cur[r], 1);
    packed[pos] = make_int2(cols[e], __float_as_int(vals[e]));
}

// ---------------- fused SpMM(gather) + GEMM[128x128] + tanh + l2 + acc ----------------
#define FRPB 16  // rows per block (4 waves x 4 rows)
__global__ __launch_bounds__(256)
void spmm_fused(const int* __restrict__ rowptr, const int2* __restrict__ packed,
                const float* __restrict__ emb, const float* __restrict__ W,
                const float* __restrict__ aux_in, float* __restrict__ aux_out,
                float* __restrict__ n_out, int N)
{
    __shared__ __align__(16) float Ws[128][128];   // 64 KB
    __shared__ float hs[4][128];

    const int tid = threadIdx.x;
#pragma unroll
    for (int j = 0; j < 16; j++) {
        int f = j * 256 + tid;                     // float4 index 0..4095
        ((float4*)Ws)[f] = ((const float4*)W)[f];
    }
    __syncthreads();

    const int wv = tid >> 6, lane = tid & 63;
    const int base = blockIdx.x * FRPB + wv * 4;

    for (int rr = 0; rr < 4; ++rr) {
        int r = base + rr;
        if (r >= N) break;                         // wave-uniform
        int s = rowptr[r], e = rowptr[r + 1];

        float2 a0 = make_float2(0.f, 0.f), a1 = make_float2(0.f, 0.f);
        int i = s;
        for (; i + 1 < e; i += 2) {
            int2 p0 = packed[i], p1 = packed[i + 1];
            float2 m0 = *(const float2*)(emb + (size_t)p0.x * 128 + lane * 2);
            float2 m1 = *(const float2*)(emb + (size_t)p1.x * 128 + lane * 2);
            float v0 = __int_as_float(p0.y), v1 = __int_as_float(p1.y);
            a0.x += v0 * m0.x; a0.y += v0 * m0.y;
            a1.x += v1 * m1.x; a1.y += v1 * m1.y;
        }
        if (i < e) {
            int2 p0 = packed[i];
            float2 m0 = *(const float2*)(emb + (size_t)p0.x * 128 + lane * 2);
            float v0 = __int_as_float(p0.y);
            a0.x += v0 * m0.x; a0.y += v0 * m0.y;
        }
        hs[wv][lane * 2]     = a0.x + a1.x;
        hs[wv][lane * 2 + 1] = a0.y + a1.y;
        // wave-lockstep RAW on LDS: compiler inserts lgkmcnt

        float ox = 0.f, oy = 0.f;
#pragma unroll 8
        for (int k = 0; k < 128; k++) {
            float hk = hs[wv][k];                  // LDS broadcast
            float2 wk = *(const float2*)&Ws[k][lane * 2];
            ox += hk * wk.x; oy += hk * wk.y;
        }
        ox = tanhf(ox); oy = tanhf(oy);
        float ss = ox * ox + oy * oy;
#pragma unroll
        for (int m = 32; m >= 1; m >>= 1) ss += __shfl_xor(ss, m);
        float sc = 1.f / fmaxf(sqrtf(ss), 1e-12f);
        ox *= sc; oy *= sc;

        size_t off = (size_t)r * 128 + lane * 2;
        *(float2*)(n_out + off) = make_float2(ox, oy);
        float2 ai = *(const float2*)(aux_in + off);
        *(float2*)(aux_out + off) = make_float2(ai.x + ox, ai.y + oy);
    }
}

// ---------------- launch ----------------
extern "C" void kernel_launch(void* const* d_in, const int* in_sizes, int n_in,
                              void* d_out, int out_size, void* d_ws, size_t ws_size,
                              hipStream_t stream)
{
    const float* feat  = (const float*)d_in[0];
    const int*   srows = (const int*)  d_in[1];
    const int*   scols = (const int*)  d_in[2];
    const float* svals = (const float*)d_in[3];
    const float* Wf0   = (const float*)d_in[4];
    const float* bf0   = (const float*)d_in[5];
    const float* Wf1   = (const float*)d_in[6];
    const float* bf1   = (const float*)d_in[7];
    const float* Wg    = (const float*)d_in[8];
    const float* Wemb  = (const float*)d_in[9];
    const float* bemb  = (const float*)d_in[10];
    const float* Wl    = (const float*)d_in[11];
    const float* bl    = (const float*)d_in[12];
    const float* Wr    = (const float*)d_in[13];
    const float* br    = (const float*)d_in[14];

    const int M = in_sizes[0] / 512;   // 100000 (= N nodes)
    const int E = in_sizes[1];         // 3200000

    float* out  = (float*)d_out;
    float* embO = out;
    float* lftO = out + (size_t)M * 128;
    float* rgtO = out + (size_t)M * 256;

    // workspace layout (~78 MB): x | rowptr | cnt | packed | tilesum
    float* ws = (float*)d_ws;
    float* x  = ws;                                       // [M,128]
    int*   ip = (int*)(ws + (size_t)M * 128);
    int*   rowptr = ip;                                   // M+1 ints
    int*   cnt    = ip + (((size_t)M + 2) & ~(size_t)1);  // M ints (also cursor)
    int2*  packed = (int2*)(cnt + M);                     // E pairs (8B aligned)
    int*   tilesum = (int*)(packed + E);                  // ~49 ints

    float* x1 = out;     // [M,256] scratch in d_out (emb+lft regions)
    float* n0 = rgtO;    // scratch in rgt region until step 10
    float* n1 = x;       // reuse x region
    float* acc = embO;   // gnn_acc in emb region

    dim3 blk(256);
    const int gm = (M + BM - 1) / BM;
    const int ge = (E + 255) / 256;
    const int numTiles = (M + SCAN_TILE - 1) / SCAN_TILE;

    // --- CSR build ---
    hipMemsetAsync(cnt, 0, (size_t)M * 4, stream);
    hist_k<<<ge, blk, 0, stream>>>(srows, cnt, E);
    scan_phaseA<<<numTiles, blk, 0, stream>>>(cnt, tilesum, M);
    scan_phaseB<<<1, 64, 0, stream>>>(tilesum, rowptr, numTiles, M);
    scan_phaseC<<<numTiles, blk, 0, stream>>>(cnt, tilesum, rowptr, M);
    hipMemsetAsync(cnt, 0, (size_t)M * 4, stream);
    reorder_k<<<ge, blk, 0, stream>>>(srows, scols, svals, rowptr, cnt, packed, E);

    // --- network ---
    // 1. x1 = tanh(feat @ Wf0 + bf0)
    gemm_ep<true,false,false,false><<<dim3(gm,2),blk,0,stream>>>(feat,Wf0,bf0,nullptr,nullptr,nullptr,x1,M,512,256);
    // 2. x = tanh(x1 @ Wf1 + bf1)
    gemm_ep<true,false,false,false><<<dim3(gm,1),blk,0,stream>>>(x1,Wf1,bf1,nullptr,nullptr,nullptr,x,M,256,128);
    // 3+4. n0 = l2norm(tanh(spmm(x) @ Wg0)); acc = x + n0
    spmm_fused<<<(M + FRPB - 1) / FRPB, blk, 0, stream>>>(rowptr, packed, x, Wg, x, acc, n0, M);
    // 5+6. n1 = l2norm(tanh(spmm(n0) @ Wg1)); acc += n1
    spmm_fused<<<(M + FRPB - 1) / FRPB, blk, 0, stream>>>(rowptr, packed, n0, Wg + 128*128, acc, acc, n1, M);
    // 7. emb = l2norm(acc @ Wemb + bemb) (in-place over acc; block reads only its own rows first)
    gemm_ep<false,true,false,false><<<dim3(gm,1),blk,0,stream>>>(acc,Wemb,bemb,nullptr,nullptr,nullptr,embO,M,128,128);
    // 8. lft0 = tanh(n1 @ Wl0 + bl0) + n1
    gemm_ep<true,false,true,false><<<dim3(gm,1),blk,0,stream>>>(n1,Wl,bl,n1,nullptr,nullptr,lftO,M,128,128);
    // 9. lft = tanh(lft0 @ Wl1 + bl1)
    gemm_ep<true,false,false,false><<<dim3(gm,1),blk,0,stream>>>(lftO,Wl+128*128,bl+128,nullptr,nullptr,nullptr,lftO,M,128,128);
    // 10. rgt0 = tanh(n1 @ Wr0 + br0) + n1
    gemm_ep<true,false,true,false><<<dim3(gm,1),blk,0,stream>>>(n1,Wr,br,n1,nullptr,nullptr,rgtO,M,128,128);
    // 11. rgt = tanh(rgt0 @ Wr1 + br1)
    gemm_ep<true,false,false,false><<<dim3(gm,1),blk,0,stream>>>(rgtO,Wr+128*128,br+128,nullptr,nullptr,nullptr,rgtO,M,128,128);
}

// Round 3
// 1633.774 us; speedup vs baseline: 7.0822x; 1.4756x over previous
//
#include <hip/hip_runtime.h>
#include <math.h>

// ============ old 64x128 tiled GEMM with fused epilogue (proven) ============
#define BM 64
#define BK 32
#define LDT 68

template<bool TANH, bool L2, bool RESID, bool AUX>
__global__ __launch_bounds__(256)
void gemm_ep(const float* __restrict__ A, const float* __restrict__ W,
             const float* __restrict__ bias, const float* __restrict__ resid,
             const float* __restrict__ aux_in, float* __restrict__ aux_out,
             float* __restrict__ out, int M, int K, int Ncols)
{
    __shared__ __align__(16) float As[BK][LDT];
    __shared__ __align__(16) float Ws[BK][128];

    const int tid  = threadIdx.x;
    const int row0 = blockIdx.x * BM;
    const int col0 = blockIdx.y * 128;
    const int cg   = tid & 31;
    const int rg   = tid >> 5;

    float acc[8][4];
#pragma unroll
    for (int i = 0; i < 8; i++)
#pragma unroll
        for (int j = 0; j < 4; j++) acc[i][j] = 0.f;

    for (int k0 = 0; k0 < K; k0 += BK) {
#pragma unroll
        for (int jj = 0; jj < 2; jj++) {
            int f  = jj * 256 + tid;
            int r  = f >> 3;
            int c4 = (f & 7) << 2;
            float4 a = make_float4(0.f, 0.f, 0.f, 0.f);
            int row = row0 + r;
            if (row < M) a = *(const float4*)(A + (size_t)row * K + k0 + c4);
            As[c4 + 0][r] = a.x; As[c4 + 1][r] = a.y;
            As[c4 + 2][r] = a.z; As[c4 + 3][r] = a.w;
        }
#pragma unroll
        for (int jj = 0; jj < 4; jj++) {
            int f  = jj * 256 + tid;
            int k  = f >> 5;
            int c4 = (f & 31) << 2;
            *(float4*)&Ws[k][c4] = *(const float4*)(W + (size_t)(k0 + k) * Ncols + col0 + c4);
        }
        __syncthreads();
#pragma unroll
        for (int k = 0; k < BK; k++) {
            float4 a0 = *(const float4*)&As[k][rg * 8];
            float4 a1 = *(const float4*)&As[k][rg * 8 + 4];
            float4 w  = *(const float4*)&Ws[k][cg * 4];
            float av[8] = {a0.x, a0.y, a0.z, a0.w, a1.x, a1.y, a1.z, a1.w};
#pragma unroll
            for (int i = 0; i < 8; i++) {
                acc[i][0] += av[i] * w.x;
                acc[i][1] += av[i] * w.y;
                acc[i][2] += av[i] * w.z;
                acc[i][3] += av[i] * w.w;
            }
        }
        __syncthreads();
    }

    float bv[4] = {0.f, 0.f, 0.f, 0.f};
    if (bias) {
        float4 b4 = *(const float4*)(bias + col0 + cg * 4);
        bv[0] = b4.x; bv[1] = b4.y; bv[2] = b4.z; bv[3] = b4.w;
    }
#pragma unroll
    for (int i = 0; i < 8; i++) {
        int row = row0 + rg * 8 + i;
        if (row >= M) continue;
        float v[4];
#pragma unroll
        for (int j = 0; j < 4; j++) v[j] = acc[i][j] + bv[j];
        if (TANH) {
#pragma unroll
            for (int j = 0; j < 4; j++) v[j] = tanhf(v[j]);
        }
        if (RESID) {
            float4 rr = *(const float4*)(resid + (size_t)row * Ncols + col0 + cg * 4);
            v[0] += rr.x; v[1] += rr.y; v[2] += rr.z; v[3] += rr.w;
        }
        if (L2) {
            float s = v[0]*v[0] + v[1]*v[1] + v[2]*v[2] + v[3]*v[3];
#pragma unroll
            for (int m = 16; m >= 1; m >>= 1) s += __shfl_xor(s, m);
            float sc = 1.f / fmaxf(sqrtf(s), 1e-12f);
#pragma unroll
            for (int j = 0; j < 4; j++) v[j] *= sc;
        }
        float4 o = make_float4(v[0], v[1], v[2], v[3]);
        *(float4*)(out + (size_t)row * Ncols + col0 + cg * 4) = o;
        if (AUX) {
            float4 ai = *(const float4*)(aux_in + (size_t)row * Ncols + col0 + cg * 4);
            float4 ao = make_float4(ai.x + o.x, ai.y + o.y, ai.z + o.z, ai.w + o.w);
            *(float4*)(aux_out + (size_t)row * Ncols + col0 + cg * 4) = ao;
        }
    }
}

// ============ new 128x128 tiled GEMM (for big-K reductions) ============
#define GBK 32
#define GLD 132   // padded leading dim

template<bool TANH>
__global__ __launch_bounds__(256)
void gemm128(const float* __restrict__ A, const float* __restrict__ W,
             const float* __restrict__ bias, float* __restrict__ out,
             int M, int K, int Ncols)
{
    __shared__ __align__(16) float As[GBK][GLD];   // transposed A tile
    __shared__ __align__(16) float Ws[GBK][GLD];

    const int tid  = threadIdx.x;
    const int row0 = blockIdx.x * 128;
    const int col0 = blockIdx.y * 128;
    const int tr   = tid >> 4;    // 0..15 -> rows tr*8..+7
    const int tc   = tid & 15;    // cols tc*4..+3 and 64+tc*4..+3

    float acc[8][8];
#pragma unroll
    for (int i = 0; i < 8; i++)
#pragma unroll
        for (int j = 0; j < 8; j++) acc[i][j] = 0.f;

    for (int k0 = 0; k0 < K; k0 += GBK) {
        // A tile transposed: 1024 float4 loads, 4 per thread
#pragma unroll
        for (int jj = 0; jj < 4; jj++) {
            int f  = jj * 256 + tid;        // 0..1023
            int r  = f >> 3;                // 0..127
            int c4 = (f & 7) << 2;          // 0..28
            float4 a = make_float4(0.f, 0.f, 0.f, 0.f);
            int row = row0 + r;
            if (row < M) a = *(const float4*)(A + (size_t)row * K + k0 + c4);
            As[c4 + 0][r] = a.x; As[c4 + 1][r] = a.y;
            As[c4 + 2][r] = a.z; As[c4 + 3][r] = a.w;
        }
        // W tile: 1024 float4 loads
#pragma unroll
        for (int jj = 0; jj < 4; jj++) {
            int f  = jj * 256 + tid;
            int k  = f >> 5;
            int c4 = (f & 31) << 2;
            *(float4*)&Ws[k][c4] = *(const float4*)(W + (size_t)(k0 + k) * Ncols + col0 + c4);
        }
        __syncthreads();
#pragma unroll
        for (int k = 0; k < GBK; k++) {
            float4 a0 = *(const float4*)&As[k][tr * 8];
            float4 a1 = *(const float4*)&As[k][tr * 8 + 4];
            float4 w0 = *(const float4*)&Ws[k][tc * 4];
            float4 w1 = *(const float4*)&Ws[k][64 + tc * 4];
            float av[8] = {a0.x, a0.y, a0.z, a0.w, a1.x, a1.y, a1.z, a1.w};
            float wv[8] = {w0.x, w0.y, w0.z, w0.w, w1.x, w1.y, w1.z, w1.w};
#pragma unroll
            for (int i = 0; i < 8; i++)
#pragma unroll
                for (int j = 0; j < 8; j++) acc[i][j] += av[i] * wv[j];
        }
        __syncthreads();
    }

    float bv[8];
    {
        float4 b0 = *(const float4*)(bias + col0 + tc * 4);
        float4 b1 = *(const float4*)(bias + col0 + 64 + tc * 4);
        bv[0]=b0.x; bv[1]=b0.y; bv[2]=b0.z; bv[3]=b0.w;
        bv[4]=b1.x; bv[5]=b1.y; bv[6]=b1.z; bv[7]=b1.w;
    }
#pragma unroll
    for (int i = 0; i < 8; i++) {
        int row = row0 + tr * 8 + i;
        if (row >= M) continue;
        float v[8];
#pragma unroll
        for (int j = 0; j < 8; j++) {
            v[j] = acc[i][j] + bv[j];
            if (TANH) v[j] = tanhf(v[j]);
        }
        *(float4*)(out + (size_t)row * Ncols + col0 + tc * 4)      = make_float4(v[0],v[1],v[2],v[3]);
        *(float4*)(out + (size_t)row * Ncols + col0 + 64 + tc * 4) = make_float4(v[4],v[5],v[6],v[7]);
    }
}

// ============ CSR build ============
__global__ __launch_bounds__(256)
void hist_k(const int* __restrict__ rows, int* __restrict__ cnt, int E)
{
    int e = blockIdx.x * 256 + threadIdx.x;
    if (e < E) atomicAdd(&cnt[rows[e]], 1);
}

#define SCAN_TILE 2048

__global__ __launch_bounds__(256)
void scan_phaseA(const int* __restrict__ cnt, int* __restrict__ tilesum, int N)
{
    __shared__ int sdata[256];
    int base = blockIdx.x * SCAN_TILE + threadIdx.x * 8;
    int s = 0;
#pragma unroll
    for (int j = 0; j < 8; j++) { int i = base + j; if (i < N) s += cnt[i]; }
    sdata[threadIdx.x] = s; __syncthreads();
    for (int off = 128; off > 0; off >>= 1) {
        if (threadIdx.x < off) sdata[threadIdx.x] += sdata[threadIdx.x + off];
        __syncthreads();
    }
    if (threadIdx.x == 0) tilesum[blockIdx.x] = sdata[0];
}

__global__ void scan_phaseB(int* __restrict__ tilesum, int* __restrict__ rowptr,
                            int numTiles, int N)
{
    if (threadIdx.x == 0 && blockIdx.x == 0) {
        int run = 0;
        for (int t = 0; t < numTiles; t++) { int v = tilesum[t]; tilesum[t] = run; run += v; }
        rowptr[N] = run;
    }
}

__global__ __launch_bounds__(256)
void scan_phaseC(const int* __restrict__ cnt, const int* __restrict__ tilesum,
                 int* __restrict__ rowptr, int N)
{
    __shared__ int sdata[256];
    int base = blockIdx.x * SCAN_TILE + threadIdx.x * 8;
    int loc[8]; int s = 0;
#pragma unroll
    for (int j = 0; j < 8; j++) {
        int i = base + j; int v = (i < N) ? cnt[i] : 0;
        loc[j] = s; s += v;
    }
    sdata[threadIdx.x] = s; __syncthreads();
    int x = s;
    for (int off = 1; off < 256; off <<= 1) {
        int t = 0;
        if (threadIdx.x >= off) t = sdata[threadIdx.x - off];
        __syncthreads();
        x += t;
        sdata[threadIdx.x] = x;
        __syncthreads();
    }
    int texcl = x - s + tilesum[blockIdx.x];
#pragma unroll
    for (int j = 0; j < 8; j++) {
        int i = base + j;
        if (i < N) rowptr[i] = texcl + loc[j];
    }
}

__global__ __launch_bounds__(256)
void reorder_k(const int* __restrict__ rows, const int* __restrict__ cols,
               const float* __restrict__ vals, const int* __restrict__ rowptr,
               int* __restrict__ cur, int2* __restrict__ packed, int E)
{
    int e = blockIdx.x * 256 + threadIdx.x;
    if (e >= E) return;
    int r = rows[e];
    int pos = rowptr[r] + atomicAdd(&cur[r], 1);
    packed[pos] = make_int2(cols[e], __float_as_int(vals[e]));
}

// ============ pure CSR SpMM: wave per row, deep unroll for MLP ============
__global__ __launch_bounds__(256)
void spmm_csr(const int* __restrict__ rowptr, const int2* __restrict__ packed,
              const float* __restrict__ emb, float* __restrict__ h, int N)
{
    const int wv = threadIdx.x >> 6, lane = threadIdx.x & 63;
    const int r = blockIdx.x * 4 + wv;
    if (r >= N) return;
    const int s = rowptr[r], e = rowptr[r + 1];
    const int l2 = lane * 2;

    float2 a0 = make_float2(0.f,0.f), a1 = make_float2(0.f,0.f);
    float2 a2 = make_float2(0.f,0.f), a3 = make_float2(0.f,0.f);
    int i = s;
    for (; i + 8 <= e; i += 8) {
        int2 p0 = packed[i+0], p1 = packed[i+1], p2 = packed[i+2], p3 = packed[i+3];
        int2 p4 = packed[i+4], p5 = packed[i+5], p6 = packed[i+6], p7 = packed[i+7];
        float2 m0 = *(const float2*)(emb + ((size_t)p0.x << 7) + l2);
        float2 m1 = *(const float2*)(emb + ((size_t)p1.x << 7) + l2);
        float2 m2 = *(const float2*)(emb + ((size_t)p2.x << 7) + l2);
        float2 m3 = *(const float2*)(emb + ((size_t)p3.x << 7) + l2);
        float2 m4 = *(const float2*)(emb + ((size_t)p4.x << 7) + l2);
        float2 m5 = *(const float2*)(emb + ((size_t)p5.x << 7) + l2);
        float2 m6 = *(const float2*)(emb + ((size_t)p6.x << 7) + l2);
        float2 m7 = *(const float2*)(emb + ((size_t)p7.x << 7) + l2);
        float v0 = __int_as_float(p0.y), v1 = __int_as_float(p1.y);
        float v2 = __int_as_float(p2.y), v3 = __int_as_float(p3.y);
        float v4 = __int_as_float(p4.y), v5 = __int_as_float(p5.y);
        float v6 = __int_as_float(p6.y), v7 = __int_as_float(p7.y);
        a0.x += v0*m0.x; a0.y += v0*m0.y;  a1.x += v1*m1.x; a1.y += v1*m1.y;
        a2.x += v2*m2.x; a2.y += v2*m2.y;  a3.x += v3*m3.x; a3.y += v3*m3.y;
        a0.x += v4*m4.x; a0.y += v4*m4.y;  a1.x += v5*m5.x; a1.y += v5*m5.y;
        a2.x += v6*m6.x; a2.y += v6*m6.y;  a3.x += v7*m7.x; a3.y += v7*m7.y;
    }
    for (; i < e; i++) {
        int2 p = packed[i];
        float2 m = *(const float2*)(emb + ((size_t)p.x << 7) + l2);
        float v = __int_as_float(p.y);
        a0.x += v*m.x; a0.y += v*m.y;
    }
    float2 t;
    t.x = (a0.x + a1.x) + (a2.x + a3.x);
    t.y = (a0.y + a1.y) + (a2.y + a3.y);
    *(float2*)(h + ((size_t)r << 7) + l2) = t;
}

// ============ launch ============
extern "C" void kernel_launch(void* const* d_in, const int* in_sizes, int n_in,
                              void* d_out, int out_size, void* d_ws, size_t ws_size,
                              hipStream_t stream)
{
    const float* feat  = (const float*)d_in[0];
    const int*   srows = (const int*)  d_in[1];
    const int*   scols = (const int*)  d_in[2];
    const float* svals = (const float*)d_in[3];
    const float* Wf0   = (const float*)d_in[4];
    const float* bf0   = (const float*)d_in[5];
    const float* Wf1   = (const float*)d_in[6];
    const float* bf1   = (const float*)d_in[7];
    const float* Wg    = (const float*)d_in[8];
    const float* Wemb  = (const float*)d_in[9];
    const float* bemb  = (const float*)d_in[10];
    const float* Wl    = (const float*)d_in[11];
    const float* bl    = (const float*)d_in[12];
    const float* Wr    = (const float*)d_in[13];
    const float* br    = (const float*)d_in[14];

    const int M = in_sizes[0] / 512;   // 100000 nodes
    const int E = in_sizes[1];         // 3200000 edges

    float* out  = (float*)d_out;
    float* embO = out;                        // [M,128]
    float* lftO = out + (size_t)M * 128;
    float* rgtO = out + (size_t)M * 256;

    // ws: x[M,128] | rowptr | cnt | packed[E] | tilesum   (~78 MB)
    float* ws = (float*)d_ws;
    float* x  = ws;
    int*   ip = (int*)(ws + (size_t)M * 128);
    int*   rowptr  = ip;                                   // M+1
    int*   cnt     = ip + (((size_t)M + 2) & ~(size_t)1);  // M (also reorder cursor)
    int2*  packed  = (int2*)(cnt + M);                     // E
    int*   tilesum = (int*)(packed + E);

    // scratch aliases inside d_out (all dead before final writes):
    float* x1  = out;     // [M,256] over emb+lft regions
    float* h   = rgtO;    // spmm accumulator (both layers)
    float* n0  = lftO;    // gnn_out layer 0
    float* n1  = x;       // gnn_out layer 1 (reuses ws.x)
    float* acc = embO;    // gnn_acc

    dim3 blk(256);
    const int gm64  = (M + BM - 1) / BM;        // 1563
    const int gm128 = (M + 127) / 128;          // 782
    const int ge    = (E + 255) / 256;
    const int numTiles = (M + SCAN_TILE - 1) / SCAN_TILE;

    // --- CSR build ---
    hipMemsetAsync(cnt, 0, (size_t)M * 4, stream);
    hist_k<<<ge, blk, 0, stream>>>(srows, cnt, E);
    scan_phaseA<<<numTiles, blk, 0, stream>>>(cnt, tilesum, M);
    scan_phaseB<<<1, 64, 0, stream>>>(tilesum, rowptr, numTiles, M);
    scan_phaseC<<<numTiles, blk, 0, stream>>>(cnt, tilesum, rowptr, M);
    hipMemsetAsync(cnt, 0, (size_t)M * 4, stream);
    reorder_k<<<ge, blk, 0, stream>>>(srows, scols, svals, rowptr, cnt, packed, E);

    // --- network ---
    // 1. x1 = tanh(feat @ Wf0 + bf0)        [M,512]->[M,256]
    gemm128<true><<<dim3(gm128,2),blk,0,stream>>>(feat, Wf0, bf0, x1, M, 512, 256);
    // 2. x = tanh(x1 @ Wf1 + bf1)           [M,256]->[M,128]
    gemm128<true><<<dim3(gm128,1),blk,0,stream>>>(x1, Wf1, bf1, x, M, 256, 128);
    // 3. h = spmm(x)
    spmm_csr<<<(M + 3) / 4, blk, 0, stream>>>(rowptr, packed, x, h, M);
    // 4. n0 = l2norm(tanh(h @ Wg0)); acc = x + n0
    gemm_ep<true,true,false,true><<<dim3(gm64,1),blk,0,stream>>>(h, Wg, nullptr, nullptr, x, acc, n0, M, 128, 128);
    // 5. h = spmm(n0)
    spmm_csr<<<(M + 3) / 4, blk, 0, stream>>>(rowptr, packed, n0, h, M);
    // 6. n1 = l2norm(tanh(h @ Wg1)); acc += n1
    gemm_ep<true,true,false,true><<<dim3(gm64,1),blk,0,stream>>>(h, Wg + 128*128, nullptr, nullptr, acc, acc, n1, M, 128, 128);
    // 7. emb = l2norm(acc @ Wemb + bemb)  (in-place: block reads only its own rows)
    gemm_ep<false,true,false,false><<<dim3(gm64,1),blk,0,stream>>>(acc, Wemb, bemb, nullptr, nullptr, nullptr, embO, M, 128, 128);
    // 8. lft0 = tanh(n1 @ Wl0 + bl0) + n1
    gemm_ep<true,false,true,false><<<dim3(gm64,1),blk,0,stream>>>(n1, Wl, bl, n1, nullptr, nullptr, lftO, M, 128, 128);
    // 9. lft = tanh(lft0 @ Wl1 + bl1)     (in-place)
    gemm_ep<true,false,false,false><<<dim3(gm64,1),blk,0,stream>>>(lftO, Wl + 128*128, bl + 128, nullptr, nullptr, nullptr, lftO, M, 128, 128);
    // 10. rgt0 = tanh(n1 @ Wr0 + br0) + n1
    gemm_ep<true,false,true,false><<<dim3(gm64,1),blk,0,stream>>>(n1, Wr, br, n1, nullptr, nullptr, rgtO, M, 128, 128);
    // 11. rgt = tanh(rgt0 @ Wr1 + br1)    (in-place)
    gemm_ep<true,false,false,false><<<dim3(gm64,1),blk,0,stream>>>(rgtO, Wr + 128*128, br + 128, nullptr, nullptr, nullptr, rgtO, M, 128, 128);
}

// Round 5
// 1231.194 us; speedup vs baseline: 9.3979x; 1.3270x over previous
//
#include <hip/hip_runtime.h>
#include <math.h>

typedef short bf16x8 __attribute__((ext_vector_type(8)));
typedef float f32x4  __attribute__((ext_vector_type(4)));

__device__ __forceinline__ unsigned short f2bf(float x) {
    unsigned u = __float_as_uint(x);
    unsigned r = u + 0x7FFFu + ((u >> 16) & 1u);   // RNE, matches v_cvt
    return (unsigned short)(r >> 16);
}

// ============ weight convert+transpose: Wt[n][k] = bf16(W[k][n]) ============
__global__ __launch_bounds__(256)
void wconv(const float* __restrict__ W, unsigned short* __restrict__ Wt, int K, int N)
{
    int id = blockIdx.x * 256 + threadIdx.x;
    if (id >= K * N) return;
    int n = id / K, k = id - n * K;            // k contiguous per run -> coalesced writes
    Wt[(size_t)n * K + k] = f2bf(W[(size_t)k * N + n]);
}

// ============ bf16 MFMA GEMM: out = ep(A_f32 @ W + bias) ============
// A [M,K] f32 (converted to bf16 in-kernel), Wt [Ncols][K] bf16 (pre-transposed).
// tile 128x128, 4 waves (2x2 of 64x64), BK=64, 16x16x32 MFMA.
template<bool TANH, bool BF16OUT>
__global__ __launch_bounds__(256)
void mfma_gemm(const float* __restrict__ A, const unsigned short* __restrict__ Wt,
               const float* __restrict__ bias, float* __restrict__ out,
               unsigned short* __restrict__ out_bf, int M, int K, int Ncols)
{
    __shared__ __align__(16) unsigned short Al[128][72];   // [m][k], 144B rows (16B mult)
    __shared__ __align__(16) unsigned short Bl[128][72];   // [n][k]

    const int tid  = threadIdx.x;
    const int row0 = blockIdx.x * 128;
    const int col0 = blockIdx.y * 128;
    const int wv   = tid >> 6, lane = tid & 63;
    const int wr   = (wv >> 1) * 64;         // wave row offset
    const int wc   = (wv & 1) * 64;          // wave col offset
    const int lr   = lane & 15;              // fragment row/col index
    const int lk   = (lane >> 4) * 8;        // fragment k offset

    f32x4 acc[4][4];
#pragma unroll
    for (int m = 0; m < 4; m++)
#pragma unroll
        for (int n = 0; n < 4; n++)
#pragma unroll
            for (int j = 0; j < 4; j++) acc[m][n][j] = 0.f;

    for (int k0 = 0; k0 < K; k0 += 64) {
        // stage A (f32 -> bf16): 128 rows x 16 float4-slots = 2048, 8 per thread
#pragma unroll
        for (int i = 0; i < 8; i++) {
            int f  = i * 256 + tid;
            int r  = f >> 4;                 // 0..127
            int c4 = (f & 15) << 2;          // 0..60, 4 elems per slot
            float4 a = make_float4(0.f, 0.f, 0.f, 0.f);
            if (row0 + r < M) a = *(const float4*)(A + (size_t)(row0 + r) * K + k0 + c4);
            *(ushort4*)&Al[r][c4] = make_ushort4(f2bf(a.x), f2bf(a.y), f2bf(a.z), f2bf(a.w));
        }
        // stage B (already bf16): 128 rows x 8 bf16x8-slots = 1024, 4 per thread
        // (R4 BUG was here: ushort4 copy with stride-8 k8 left half of Bl uninitialized)
#pragma unroll
        for (int i = 0; i < 4; i++) {
            int f  = i * 256 + tid;
            int n  = f >> 3;                 // 0..127
            int k8 = (f & 7) << 3;           // 0..56, 8 elems per slot
            *(bf16x8*)&Bl[n][k8] = *(const bf16x8*)(Wt + (size_t)(col0 + n) * K + k0 + k8);
        }
        __syncthreads();
#pragma unroll
        for (int kk = 0; kk < 64; kk += 32) {
            bf16x8 af[4], bfr[4];
#pragma unroll
            for (int m = 0; m < 4; m++) af[m]  = *(const bf16x8*)&Al[wr + m * 16 + lr][kk + lk];
#pragma unroll
            for (int n = 0; n < 4; n++) bfr[n] = *(const bf16x8*)&Bl[wc + n * 16 + lr][kk + lk];
#pragma unroll
            for (int m = 0; m < 4; m++)
#pragma unroll
                for (int n = 0; n < 4; n++)
                    acc[m][n] = __builtin_amdgcn_mfma_f32_16x16x32_bf16(af[m], bfr[n], acc[m][n], 0, 0, 0);
        }
        __syncthreads();
    }

    // epilogue: D elem j -> row = (lane>>4)*4 + j, col = lane&15  [guide m89/m91]
    const int rbase = (lane >> 4) * 4;
#pragma unroll
    for (int n = 0; n < 4; n++) {
        int col = col0 + wc + n * 16 + lr;
        float b = bias[col];
#pragma unroll
        for (int m = 0; m < 4; m++) {
#pragma unroll
            for (int j = 0; j < 4; j++) {
                int row = row0 + wr + m * 16 + rbase + j;
                if (row < M) {
                    float v = acc[m][n][j] + b;
                    if (TANH) v = tanhf(v);
                    out[(size_t)row * Ncols + col] = v;
                    if (BF16OUT) out_bf[(size_t)row * Ncols + col] = f2bf(v);
                }
            }
        }
    }
}

// ============ 64x128 tiled f32 GEMM with fused epilogue (proven) ============
#define BM 64
#define BK 32
#define LDT 68

template<bool TANH, bool L2, bool RESID, bool AUX, bool OBF>
__global__ __launch_bounds__(256)
void gemm_ep(const float* __restrict__ A, const float* __restrict__ W,
             const float* __restrict__ bias, const float* __restrict__ resid,
             const float* __restrict__ aux_in, float* __restrict__ aux_out,
             void* __restrict__ out_v, int M, int K, int Ncols)
{
    __shared__ __align__(16) float As[BK][LDT];
    __shared__ __align__(16) float Ws[BK][128];

    const int tid  = threadIdx.x;
    const int row0 = blockIdx.x * BM;
    const int col0 = blockIdx.y * 128;
    const int cg   = tid & 31;
    const int rg   = tid >> 5;

    float acc[8][4];
#pragma unroll
    for (int i = 0; i < 8; i++)
#pragma unroll
        for (int j = 0; j < 4; j++) acc[i][j] = 0.f;

    for (int k0 = 0; k0 < K; k0 += BK) {
#pragma unroll
        for (int jj = 0; jj < 2; jj++) {
            int f  = jj * 256 + tid;
            int r  = f >> 3;
            int c4 = (f & 7) << 2;
            float4 a = make_float4(0.f, 0.f, 0.f, 0.f);
            int row = row0 + r;
            if (row < M) a = *(const float4*)(A + (size_t)row * K + k0 + c4);
            As[c4 + 0][r] = a.x; As[c4 + 1][r] = a.y;
            As[c4 + 2][r] = a.z; As[c4 + 3][r] = a.w;
        }
#pragma unroll
        for (int jj = 0; jj < 4; jj++) {
            int f  = jj * 256 + tid;
            int k  = f >> 5;
            int c4 = (f & 31) << 2;
            *(float4*)&Ws[k][c4] = *(const float4*)(W + (size_t)(k0 + k) * Ncols + col0 + c4);
        }
        __syncthreads();
#pragma unroll
        for (int k = 0; k < BK; k++) {
            float4 a0 = *(const float4*)&As[k][rg * 8];
            float4 a1 = *(const float4*)&As[k][rg * 8 + 4];
            float4 w  = *(const float4*)&Ws[k][cg * 4];
            float av[8] = {a0.x, a0.y, a0.z, a0.w, a1.x, a1.y, a1.z, a1.w};
#pragma unroll
            for (int i = 0; i < 8; i++) {
                acc[i][0] += av[i] * w.x;
                acc[i][1] += av[i] * w.y;
                acc[i][2] += av[i] * w.z;
                acc[i][3] += av[i] * w.w;
            }
        }
        __syncthreads();
    }

    float bv[4] = {0.f, 0.f, 0.f, 0.f};
    if (bias) {
        float4 b4 = *(const float4*)(bias + col0 + cg * 4);
        bv[0] = b4.x; bv[1] = b4.y; bv[2] = b4.z; bv[3] = b4.w;
    }
#pragma unroll
    for (int i = 0; i < 8; i++) {
        int row = row0 + rg * 8 + i;
        if (row >= M) continue;
        float v[4];
#pragma unroll
        for (int j = 0; j < 4; j++) v[j] = acc[i][j] + bv[j];
        if (TANH) {
#pragma unroll
            for (int j = 0; j < 4; j++) v[j] = tanhf(v[j]);
        }
        if (RESID) {
            float4 rr = *(const float4*)(resid + (size_t)row * Ncols + col0 + cg * 4);
            v[0] += rr.x; v[1] += rr.y; v[2] += rr.z; v[3] += rr.w;
        }
        if (L2) {
            float s = v[0]*v[0] + v[1]*v[1] + v[2]*v[2] + v[3]*v[3];
#pragma unroll
            for (int m = 16; m >= 1; m >>= 1) s += __shfl_xor(s, m);
            float sc = 1.f / fmaxf(sqrtf(s), 1e-12f);
#pragma unroll
            for (int j = 0; j < 4; j++) v[j] *= sc;
        }
        if (OBF) {
            *(ushort4*)((unsigned short*)out_v + (size_t)row * Ncols + col0 + cg * 4) =
                make_ushort4(f2bf(v[0]), f2bf(v[1]), f2bf(v[2]), f2bf(v[3]));
        } else {
            *(float4*)((float*)out_v + (size_t)row * Ncols + col0 + cg * 4) =
                make_float4(v[0], v[1], v[2], v[3]);
        }
        if (AUX) {
            float4 ai = *(const float4*)(aux_in + (size_t)row * Ncols + col0 + cg * 4);
            *(float4*)(aux_out + (size_t)row * Ncols + col0 + cg * 4) =
                make_float4(ai.x + v[0], ai.y + v[1], ai.z + v[2], ai.w + v[3]);
        }
    }
}

// ============ CSR build ============
__global__ __launch_bounds__(256)
void hist_k(const int* __restrict__ rows, int* __restrict__ cnt, int E)
{
    int e = blockIdx.x * 256 + threadIdx.x;
    if (e < E) atomicAdd(&cnt[rows[e]], 1);
}

#define SCAN_TILE 2048

__global__ __launch_bounds__(256)
void scan_phaseA(const int* __restrict__ cnt, int* __restrict__ tilesum, int N)
{
    __shared__ int sdata[256];
    int base = blockIdx.x * SCAN_TILE + threadIdx.x * 8;
    int s = 0;
#pragma unroll
    for (int j = 0; j < 8; j++) { int i = base + j; if (i < N) s += cnt[i]; }
    sdata[threadIdx.x] = s; __syncthreads();
    for (int off = 128; off > 0; off >>= 1) {
        if (threadIdx.x < off) sdata[threadIdx.x] += sdata[threadIdx.x + off];
        __syncthreads();
    }
    if (threadIdx.x == 0) tilesum[blockIdx.x] = sdata[0];
}

__global__ void scan_phaseB(int* __restrict__ tilesum, int* __restrict__ rowptr,
                            int numTiles, int N)
{
    if (threadIdx.x == 0 && blockIdx.x == 0) {
        int run = 0;
        for (int t = 0; t < numTiles; t++) { int v = tilesum[t]; tilesum[t] = run; run += v; }
        rowptr[N] = run;
    }
}

__global__ __launch_bounds__(256)
void scan_phaseC(const int* __restrict__ cnt, const int* __restrict__ tilesum,
                 int* __restrict__ rowptr, int N)
{
    __shared__ int sdata[256];
    int base = blockIdx.x * SCAN_TILE + threadIdx.x * 8;
    int loc[8]; int s = 0;
#pragma unroll
    for (int j = 0; j < 8; j++) {
        int i = base + j; int v = (i < N) ? cnt[i] : 0;
        loc[j] = s; s += v;
    }
    sdata[threadIdx.x] = s; __syncthreads();
    int x = s;
    for (int off = 1; off < 256; off <<= 1) {
        int t = 0;
        if (threadIdx.x >= off) t = sdata[threadIdx.x - off];
        __syncthreads();
        x += t;
        sdata[threadIdx.x] = x;
        __syncthreads();
    }
    int texcl = x - s + tilesum[blockIdx.x];
#pragma unroll
    for (int j = 0; j < 8; j++) {
        int i = base + j;
        if (i < N) rowptr[i] = texcl + loc[j];
    }
}

__global__ __launch_bounds__(256)
void reorder_k(const int* __restrict__ rows, const int* __restrict__ cols,
               const float* __restrict__ vals, const int* __restrict__ rowptr,
               int* __restrict__ cur, int2* __restrict__ packed, int E)
{
    int e = blockIdx.x * 256 + threadIdx.x;
    if (e >= E) return;
    int r = rows[e];
    int pos = rowptr[r] + atomicAdd(&cur[r], 1);
    packed[pos] = make_int2(cols[e], __float_as_int(vals[e]));
}

// ============ CSR SpMM with bf16 gathers: wave per row ============
__global__ __launch_bounds__(256)
void spmm_csr(const int* __restrict__ rowptr, const int2* __restrict__ packed,
              const unsigned short* __restrict__ embb, float* __restrict__ h, int N)
{
    const int wv = threadIdx.x >> 6, lane = threadIdx.x & 63;
    const int r = blockIdx.x * 4 + wv;
    if (r >= N) return;
    const int s = rowptr[r], e = rowptr[r + 1];
    const int l2 = lane * 2;

    float ax0=0.f,ay0=0.f,ax1=0.f,ay1=0.f,ax2=0.f,ay2=0.f,ax3=0.f,ay3=0.f;
    int i = s;
    for (; i + 8 <= e; i += 8) {
        int2 p0=packed[i+0],p1=packed[i+1],p2=packed[i+2],p3=packed[i+3];
        int2 p4=packed[i+4],p5=packed[i+5],p6=packed[i+6],p7=packed[i+7];
        unsigned m0 = *(const unsigned*)(embb + ((size_t)p0.x << 7) + l2);
        unsigned m1 = *(const unsigned*)(embb + ((size_t)p1.x << 7) + l2);
        unsigned m2 = *(const unsigned*)(embb + ((size_t)p2.x << 7) + l2);
        unsigned m3 = *(const unsigned*)(embb + ((size_t)p3.x << 7) + l2);
        unsigned m4 = *(const unsigned*)(embb + ((size_t)p4.x << 7) + l2);
        unsigned m5 = *(const unsigned*)(embb + ((size_t)p5.x << 7) + l2);
        unsigned m6 = *(const unsigned*)(embb + ((size_t)p6.x << 7) + l2);
        unsigned m7 = *(const unsigned*)(embb + ((size_t)p7.x << 7) + l2);
        float v0=__int_as_float(p0.y), v1=__int_as_float(p1.y);
        float v2=__int_as_float(p2.y), v3=__int_as_float(p3.y);
        float v4=__int_as_float(p4.y), v5=__int_as_float(p5.y);
        float v6=__int_as_float(p6.y), v7=__int_as_float(p7.y);
        ax0 += v0*__uint_as_float(m0<<16); ay0 += v0*__uint_as_float(m0&0xffff0000u);
        ax1 += v1*__uint_as_float(m1<<16); ay1 += v1*__uint_as_float(m1&0xffff0000u);
        ax2 += v2*__uint_as_float(m2<<16); ay2 += v2*__uint_as_float(m2&0xffff0000u);
        ax3 += v3*__uint_as_float(m3<<16); ay3 += v3*__uint_as_float(m3&0xffff0000u);
        ax0 += v4*__uint_as_float(m4<<16); ay0 += v4*__uint_as_float(m4&0xffff0000u);
        ax1 += v5*__uint_as_float(m5<<16); ay1 += v5*__uint_as_float(m5&0xffff0000u);
        ax2 += v6*__uint_as_float(m6<<16); ay2 += v6*__uint_as_float(m6&0xffff0000u);
        ax3 += v7*__uint_as_float(m7<<16); ay3 += v7*__uint_as_float(m7&0xffff0000u);
    }
    for (; i < e; i++) {
        int2 p = packed[i];
        unsigned m = *(const unsigned*)(embb + ((size_t)p.x << 7) + l2);
        float v = __int_as_float(p.y);
        ax0 += v*__uint_as_float(m<<16); ay0 += v*__uint_as_float(m&0xffff0000u);
    }
    *(float2*)(h + ((size_t)r << 7) + l2) =
        make_float2((ax0+ax1)+(ax2+ax3), (ay0+ay1)+(ay2+ay3));
}

// ============ launch ============
extern "C" void kernel_launch(void* const* d_in, const int* in_sizes, int n_in,
                              void* d_out, int out_size, void* d_ws, size_t ws_size,
                              hipStream_t stream)
{
    const float* feat  = (const float*)d_in[0];
    const int*   srows = (const int*)  d_in[1];
    const int*   scols = (const int*)  d_in[2];
    const float* svals = (const float*)d_in[3];
    const float* Wf0   = (const float*)d_in[4];
    const float* bf0   = (const float*)d_in[5];
    const float* Wf1   = (const float*)d_in[6];
    const float* bf1   = (const float*)d_in[7];
    const float* Wg    = (const float*)d_in[8];
    const float* Wemb  = (const float*)d_in[9];
    const float* bemb  = (const float*)d_in[10];
    const float* Wl    = (const float*)d_in[11];
    const float* bl    = (const float*)d_in[12];
    const float* Wr    = (const float*)d_in[13];
    const float* br    = (const float*)d_in[14];

    const int M = in_sizes[0] / 512;   // 100000 nodes
    const int E = in_sizes[1];         // 3200000 edges

    float* out  = (float*)d_out;
    float* embO = out;
    float* lftO = out + (size_t)M * 128;
    float* rgtO = out + (size_t)M * 256;

    // ws: x[M,128] f32 | rowptr | cnt | packed[E] | tilesum | Wt0 | Wt1  (~78.2 MB)
    float* ws = (float*)d_ws;
    float* x  = ws;
    int*   ip = (int*)(ws + (size_t)M * 128);
    int*   rowptr  = ip;                                   // M+1
    int*   cnt     = ip + (((size_t)M + 4) & ~(size_t)3);  // M (16B-aligned start)
    int2*  packed  = (int2*)(cnt + M);                     // E
    int*   tilesum = (int*)(packed + E);
    unsigned short* Wt0 = (unsigned short*)(tilesum + 64); // [256][512] bf16
    unsigned short* Wt1 = Wt0 + 256 * 512;                 // [128][256] bf16

    // d_out scratch timeline (all dead before final writes):
    float*          x1    = out;                                   // [M,256] emb+lft
    unsigned short* x_bf  = (unsigned short*)rgtO;                 // [M,128] bf16
    unsigned short* n0_bf = (unsigned short*)(rgtO + (size_t)M*64);// [M,128] bf16
    float*          h     = lftO;                                  // spmm accumulator
    float*          n1    = x;                                     // reuses ws.x after step 4
    float*          acc   = embO;                                  // gnn_acc

    dim3 blk(256);
    const int gm64  = (M + BM - 1) / BM;
    const int gm128 = (M + 127) / 128;
    const int ge    = (E + 255) / 256;
    const int numTiles = (M + SCAN_TILE - 1) / SCAN_TILE;

    // weight convert (independent of everything else)
    wconv<<<(512*256 + 255)/256, blk, 0, stream>>>(Wf0, Wt0, 512, 256);
    wconv<<<(256*128 + 255)/256, blk, 0, stream>>>(Wf1, Wt1, 256, 128);

    // CSR build
    hipMemsetAsync(cnt, 0, (size_t)M * 4, stream);
    hist_k<<<ge, blk, 0, stream>>>(srows, cnt, E);
    scan_phaseA<<<numTiles, blk, 0, stream>>>(cnt, tilesum, M);
    scan_phaseB<<<1, 64, 0, stream>>>(tilesum, rowptr, numTiles, M);
    scan_phaseC<<<numTiles, blk, 0, stream>>>(cnt, tilesum, rowptr, M);
    hipMemsetAsync(cnt, 0, (size_t)M * 4, stream);
    reorder_k<<<ge, blk, 0, stream>>>(srows, scols, svals, rowptr, cnt, packed, E);

    // 1. x1 = tanh(feat @ Wf0 + bf0)           [MFMA bf16]
    mfma_gemm<true,false><<<dim3(gm128,2),blk,0,stream>>>(feat, Wt0, bf0, x1, nullptr, M, 512, 256);
    // 2. x = tanh(x1 @ Wf1 + bf1); x_bf too    [MFMA bf16]
    mfma_gemm<true,true><<<dim3(gm128,1),blk,0,stream>>>(x1, Wt1, bf1, x, x_bf, M, 256, 128);
    // 3. h = spmm(x_bf)
    spmm_csr<<<(M + 3) / 4, blk, 0, stream>>>(rowptr, packed, x_bf, h, M);
    // 4. n0 = l2norm(tanh(h @ Wg0)) -> bf16; acc = x + n0
    gemm_ep<true,true,false,true,true><<<dim3(gm64,1),blk,0,stream>>>(h, Wg, nullptr, nullptr, x, acc, n0_bf, M, 128, 128);
    // 5. h = spmm(n0_bf)
    spmm_csr<<<(M + 3) / 4, blk, 0, stream>>>(rowptr, packed, n0_bf, h, M);
    // 6. n1 = l2norm(tanh(h @ Wg1)); acc += n1
    gemm_ep<true,true,false,true,false><<<dim3(gm64,1),blk,0,stream>>>(h, Wg + 128*128, nullptr, nullptr, acc, acc, n1, M, 128, 128);
    // 7. emb = l2norm(acc @ Wemb + bemb)  (in-place, block-local rows)
    gemm_ep<false,true,false,false,false><<<dim3(gm64,1),blk,0,stream>>>(acc, Wemb, bemb, nullptr, nullptr, nullptr, embO, M, 128, 128);
    // 8. lft0 = tanh(n1 @ Wl0 + bl0) + n1
    gemm_ep<true,false,true,false,false><<<dim3(gm64,1),blk,0,stream>>>(n1, Wl, bl, n1, nullptr, nullptr, lftO, M, 128, 128);
    // 9. lft = tanh(lft0 @ Wl1 + bl1)
    gemm_ep<true,false,false,false,false><<<dim3(gm64,1),blk,0,stream>>>(lftO, Wl + 128*128, bl + 128, nullptr, nullptr, nullptr, lftO, M, 128, 128);
    // 10. rgt0 = tanh(n1 @ Wr0 + br0) + n1
    gemm_ep<true,false,true,false,false><<<dim3(gm64,1),blk,0,stream>>>(n1, Wr, br, n1, nullptr, nullptr, rgtO, M, 128, 128);
    // 11. rgt = tanh(rgt0 @ Wr1 + br1)
    gemm_ep<true,false,false,false,false><<<dim3(gm64,1),blk,0,stream>>>(rgtO, Wr + 128*128, br + 128, nullptr, nullptr, nullptr, rgtO, M, 128, 128);
}

// Round 6
// 1099.360 us; speedup vs baseline: 10.5249x; 1.1199x over previous
//
#include <hip/hip_runtime.h>
#include <math.h>

typedef short bf16x8 __attribute__((ext_vector_type(8)));
typedef float f32x4  __attribute__((ext_vector_type(4)));

__device__ __forceinline__ unsigned short f2bf(float x) {
    unsigned u = __float_as_uint(x);
    unsigned r = u + 0x7FFFu + ((u >> 16) & 1u);   // RNE
    return (unsigned short)(r >> 16);
}
__device__ __forceinline__ float bf2f(unsigned short b) {
    return __uint_as_float(((unsigned)b) << 16);
}

// ============ weight convert+transpose: Wt[n][k] = bf16(W[k][n]) ============
__global__ __launch_bounds__(256)
void wconv(const float* __restrict__ W, unsigned short* __restrict__ Wt, int K, int N)
{
    int id = blockIdx.x * 256 + threadIdx.x;
    if (id >= K * N) return;
    int n = id / K, k = id - n * K;
    Wt[(size_t)n * K + k] = f2bf(W[(size_t)k * N + n]);
}

// ============ bulk f32 -> bf16 (for feat) ============
__global__ __launch_bounds__(256)
void f32_to_bf16(const float* __restrict__ in, unsigned short* __restrict__ outb, long n8)
{
    long id = (long)blockIdx.x * 256 + threadIdx.x;   // one per 8 elems
    if (id >= n8) return;
    const float4* p = (const float4*)(in + id * 8);
    float4 a = p[0], b = p[1];
    *(ushort4*)(outb + id * 8)     = make_ushort4(f2bf(a.x), f2bf(a.y), f2bf(a.z), f2bf(a.w));
    *(ushort4*)(outb + id * 8 + 4) = make_ushort4(f2bf(b.x), f2bf(b.y), f2bf(b.z), f2bf(b.w));
}

// ============ MFMA GEMM, bf16 A, B direct-from-global (L2-hot) ============
// A bf16 [M,K]; Wt bf16 [Ncols][K]. Tile 128x128, 4 waves 2x2 of 64x64, BK=64.
template<bool F32OUT, bool BF16OUT, bool TANH>
__global__ __launch_bounds__(256)
void mfma_big(const unsigned short* __restrict__ Ab, const unsigned short* __restrict__ Wt,
              const float* __restrict__ bias, float* __restrict__ out,
              unsigned short* __restrict__ out_bf, int M, int K, int Ncols)
{
    __shared__ __align__(16) unsigned short Al[128][72];   // 18.4 KB

    const int tid  = threadIdx.x;
    const int row0 = blockIdx.x * 128;
    const int col0 = blockIdx.y * 128;
    const int wv   = tid >> 6, lane = tid & 63;
    const int wr   = (wv >> 1) * 64, wc = (wv & 1) * 64;
    const int lr   = lane & 15;
    const int lk8  = (lane >> 4) * 8;

    f32x4 acc[4][4];
#pragma unroll
    for (int m = 0; m < 4; m++)
#pragma unroll
        for (int n = 0; n < 4; n++)
#pragma unroll
            for (int j = 0; j < 4; j++) acc[m][n][j] = 0.f;

    for (int k0 = 0; k0 < K; k0 += 64) {
        // stage A: 128 rows x 8 bf16x8 slots, 4 per thread
#pragma unroll
        for (int i = 0; i < 4; i++) {
            int f = i * 256 + tid;
            int r = f >> 3, k8 = (f & 7) << 3;
            bf16x8 v = {0,0,0,0,0,0,0,0};
            if (row0 + r < M) v = *(const bf16x8*)(Ab + (size_t)(row0 + r) * K + k0 + k8);
            *(bf16x8*)&Al[r][k8] = v;
        }
        __syncthreads();
#pragma unroll
        for (int kk = 0; kk < 64; kk += 32) {
            bf16x8 af[4], bf_[4];
#pragma unroll
            for (int m = 0; m < 4; m++) af[m] = *(const bf16x8*)&Al[wr + m * 16 + lr][kk + lk8];
#pragma unroll
            for (int n = 0; n < 4; n++)
                bf_[n] = *(const bf16x8*)(Wt + (size_t)(col0 + wc + n * 16 + lr) * K + k0 + kk + lk8);
#pragma unroll
            for (int m = 0; m < 4; m++)
#pragma unroll
                for (int n = 0; n < 4; n++)
                    acc[m][n] = __builtin_amdgcn_mfma_f32_16x16x32_bf16(af[m], bf_[n], acc[m][n], 0, 0, 0);
        }
        __syncthreads();
    }

    const int rbase = (lane >> 4) * 4;
#pragma unroll
    for (int n = 0; n < 4; n++) {
        int col = col0 + wc + n * 16 + lr;
        float b = bias[col];
#pragma unroll
        for (int m = 0; m < 4; m++) {
#pragma unroll
            for (int j = 0; j < 4; j++) {
                int row = row0 + wr + m * 16 + rbase + j;
                if (row < M) {
                    float v = acc[m][n][j] + b;
                    if (TANH) v = tanhf(v);
                    if (F32OUT)  out[(size_t)row * Ncols + col] = v;
                    if (BF16OUT) out_bf[(size_t)row * Ncols + col] = f2bf(v);
                }
            }
        }
    }
}

// ============ MFMA K=128 single-tile with full fused epilogue ============
// Block = 128 rows x 128 cols; wave = 32 rows x 128 cols. B direct-global (L2-hot).
template<bool ABF16, bool TANH, bool L2, bool RESID, bool AUX, bool F32OUT, bool BF16OUT, bool BIAS>
__global__ __launch_bounds__(256)
void mfma_ep(const void* __restrict__ A_, const unsigned short* __restrict__ Wt,
             const float* __restrict__ bias, const unsigned short* __restrict__ resid_bf,
             const float* __restrict__ aux_in, float* __restrict__ aux_out,
             float* __restrict__ out, unsigned short* __restrict__ out_bf, int M)
{
    __shared__ __align__(16) unsigned short Al[128][136];   // 34.8 KB

    const int tid  = threadIdx.x;
    const int row0 = blockIdx.x * 128;
    const int wv   = tid >> 6, lane = tid & 63;
    const int lr   = lane & 15;
    const int lk8  = (lane >> 4) * 8;
    const int wr   = wv * 32;

    if (ABF16) {
        const unsigned short* Ab = (const unsigned short*)A_;
#pragma unroll
        for (int i = 0; i < 8; i++) {   // 2048 bf16x8 slots
            int f = i * 256 + tid;
            int r = f >> 4, k8 = (f & 15) << 3;
            bf16x8 v = {0,0,0,0,0,0,0,0};
            if (row0 + r < M) v = *(const bf16x8*)(Ab + ((size_t)(row0 + r) << 7) + k8);
            *(bf16x8*)&Al[r][k8] = v;
        }
    } else {
        const float* Af = (const float*)A_;
#pragma unroll
        for (int i = 0; i < 16; i++) {  // 4096 float4 slots
            int f = i * 256 + tid;
            int r = f >> 5, c4 = (f & 31) << 2;
            float4 a = make_float4(0.f, 0.f, 0.f, 0.f);
            if (row0 + r < M) a = *(const float4*)(Af + ((size_t)(row0 + r) << 7) + c4);
            *(ushort4*)&Al[r][c4] = make_ushort4(f2bf(a.x), f2bf(a.y), f2bf(a.z), f2bf(a.w));
        }
    }
    __syncthreads();

    f32x4 acc[2][8];
#pragma unroll
    for (int m = 0; m < 2; m++)
#pragma unroll
        for (int n = 0; n < 8; n++)
#pragma unroll
            for (int j = 0; j < 4; j++) acc[m][n][j] = 0.f;

#pragma unroll 1
    for (int ks = 0; ks < 4; ks++) {
        bf16x8 af[2], bn[8];
#pragma unroll
        for (int m = 0; m < 2; m++) af[m] = *(const bf16x8*)&Al[wr + m * 16 + lr][ks * 32 + lk8];
#pragma unroll
        for (int n = 0; n < 8; n++)
            bn[n] = *(const bf16x8*)(Wt + (((size_t)(n * 16 + lr)) << 7) + ks * 32 + lk8);
#pragma unroll
        for (int m = 0; m < 2; m++)
#pragma unroll
            for (int n = 0; n < 8; n++)
                acc[m][n] = __builtin_amdgcn_mfma_f32_16x16x32_bf16(af[m], bn[n], acc[m][n], 0, 0, 0);
    }

    const int rbase = (lane >> 4) * 4;
    float bv[8];
#pragma unroll
    for (int n = 0; n < 8; n++) bv[n] = BIAS ? bias[n * 16 + lr] : 0.f;

#pragma unroll
    for (int m = 0; m < 2; m++) {
#pragma unroll
        for (int j = 0; j < 4; j++) {
            int row = row0 + wr + m * 16 + rbase + j;  // uniform across the 16-lane lr group
            bool ok = row < M;
            float v[8];
#pragma unroll
            for (int n = 0; n < 8; n++) {
                v[n] = acc[m][n][j] + bv[n];
                if (TANH) v[n] = tanhf(v[n]);
            }
            if (RESID) {
#pragma unroll
                for (int n = 0; n < 8; n++)
                    if (ok) v[n] += bf2f(resid_bf[((size_t)row << 7) + n * 16 + lr]);
            }
            if (L2) {
                float s = 0.f;
#pragma unroll
                for (int n = 0; n < 8; n++) s += v[n] * v[n];
#pragma unroll
                for (int msk = 8; msk >= 1; msk >>= 1) s += __shfl_xor(s, msk);
                float sc = 1.f / fmaxf(sqrtf(s), 1e-12f);
#pragma unroll
                for (int n = 0; n < 8; n++) v[n] *= sc;
            }
            if (ok) {
#pragma unroll
                for (int n = 0; n < 8; n++) {
                    size_t off = ((size_t)row << 7) + n * 16 + lr;
                    if (F32OUT)  out[off] = v[n];
                    if (BF16OUT) out_bf[off] = f2bf(v[n]);
                    if (AUX)     aux_out[off] = aux_in[off] + v[n];
                }
            }
        }
    }
}

// ============ CSR build ============
__global__ __launch_bounds__(256)
void hist_k(const int* __restrict__ rows, int* __restrict__ cnt, int E)
{
    int e = blockIdx.x * 256 + threadIdx.x;
    if (e < E) atomicAdd(&cnt[rows[e]], 1);
}

#define SCAN_TILE 2048

__global__ __launch_bounds__(256)
void scan_phaseA(const int* __restrict__ cnt, int* __restrict__ tilesum, int N)
{
    __shared__ int sdata[256];
    int base = blockIdx.x * SCAN_TILE + threadIdx.x * 8;
    int s = 0;
#pragma unroll
    for (int j = 0; j < 8; j++) { int i = base + j; if (i < N) s += cnt[i]; }
    sdata[threadIdx.x] = s; __syncthreads();
    for (int off = 128; off > 0; off >>= 1) {
        if (threadIdx.x < off) sdata[threadIdx.x] += sdata[threadIdx.x + off];
        __syncthreads();
    }
    if (threadIdx.x == 0) tilesum[blockIdx.x] = sdata[0];
}

__global__ void scan_phaseB(int* __restrict__ tilesum, int* __restrict__ rowptr,
                            int numTiles, int N)
{
    if (threadIdx.x == 0 && blockIdx.x == 0) {
        int run = 0;
        for (int t = 0; t < numTiles; t++) { int v = tilesum[t]; tilesum[t] = run; run += v; }
        rowptr[N] = run;
    }
}

__global__ __launch_bounds__(256)
void scan_phaseC(const int* __restrict__ cnt, const int* __restrict__ tilesum,
                 int* __restrict__ rowptr, int N)
{
    __shared__ int sdata[256];
    int base = blockIdx.x * SCAN_TILE + threadIdx.x * 8;
    int loc[8]; int s = 0;
#pragma unroll
    for (int j = 0; j < 8; j++) {
        int i = base + j; int v = (i < N) ? cnt[i] : 0;
        loc[j] = s; s += v;
    }
    sdata[threadIdx.x] = s; __syncthreads();
    int x = s;
    for (int off = 1; off < 256; off <<= 1) {
        int t = 0;
        if (threadIdx.x >= off) t = sdata[threadIdx.x - off];
        __syncthreads();
        x += t;
        sdata[threadIdx.x] = x;
        __syncthreads();
    }
    int texcl = x - s + tilesum[blockIdx.x];
#pragma unroll
    for (int j = 0; j < 8; j++) {
        int i = base + j;
        if (i < N) rowptr[i] = texcl + loc[j];
    }
}

__global__ __launch_bounds__(256)
void reorder_k(const int* __restrict__ rows, const int* __restrict__ cols,
               const float* __restrict__ vals, const int* __restrict__ rowptr,
               int* __restrict__ cur, int2* __restrict__ packed, int E)
{
    int e = blockIdx.x * 256 + threadIdx.x;
    if (e >= E) return;
    int r = rows[e];
    int pos = rowptr[r] + atomicAdd(&cur[r], 1);
    packed[pos] = make_int2(cols[e], __float_as_int(vals[e]));
}

// ============ CSR SpMM with bf16 gathers: wave per row ============
__global__ __launch_bounds__(256)
void spmm_csr(const int* __restrict__ rowptr, const int2* __restrict__ packed,
              const unsigned short* __restrict__ embb, float* __restrict__ h, int N)
{
    const int wv = threadIdx.x >> 6, lane = threadIdx.x & 63;
    const int r = blockIdx.x * 4 + wv;
    if (r >= N) return;
    const int s = rowptr[r], e = rowptr[r + 1];
    const int l2 = lane * 2;

    float ax0=0.f,ay0=0.f,ax1=0.f,ay1=0.f,ax2=0.f,ay2=0.f,ax3=0.f,ay3=0.f;
    int i = s;
    for (; i + 8 <= e; i += 8) {
        int2 p0=packed[i+0],p1=packed[i+1],p2=packed[i+2],p3=packed[i+3];
        int2 p4=packed[i+4],p5=packed[i+5],p6=packed[i+6],p7=packed[i+7];
        unsigned m0 = *(const unsigned*)(embb + ((size_t)p0.x << 7) + l2);
        unsigned m1 = *(const unsigned*)(embb + ((size_t)p1.x << 7) + l2);
        unsigned m2 = *(const unsigned*)(embb + ((size_t)p2.x << 7) + l2);
        unsigned m3 = *(const unsigned*)(embb + ((size_t)p3.x << 7) + l2);
        unsigned m4 = *(const unsigned*)(embb + ((size_t)p4.x << 7) + l2);
        unsigned m5 = *(const unsigned*)(embb + ((size_t)p5.x << 7) + l2);
        unsigned m6 = *(const unsigned*)(embb + ((size_t)p6.x << 7) + l2);
        unsigned m7 = *(const unsigned*)(embb + ((size_t)p7.x << 7) + l2);
        float v0=__int_as_float(p0.y), v1=__int_as_float(p1.y);
        float v2=__int_as_float(p2.y), v3=__int_as_float(p3.y);
        float v4=__int_as_float(p4.y), v5=__int_as_float(p5.y);
        float v6=__int_as_float(p6.y), v7=__int_as_float(p7.y);
        ax0 += v0*__uint_as_float(m0<<16); ay0 += v0*__uint_as_float(m0&0xffff0000u);
        ax1 += v1*__uint_as_float(m1<<16); ay1 += v1*__uint_as_float(m1&0xffff0000u);
        ax2 += v2*__uint_as_float(m2<<16); ay2 += v2*__uint_as_float(m2&0xffff0000u);
        ax3 += v3*__uint_as_float(m3<<16); ay3 += v3*__uint_as_float(m3&0xffff0000u);
        ax0 += v4*__uint_as_float(m4<<16); ay0 += v4*__uint_as_float(m4&0xffff0000u);
        ax1 += v5*__uint_as_float(m5<<16); ay1 += v5*__uint_as_float(m5&0xffff0000u);
        ax2 += v6*__uint_as_float(m6<<16); ay2 += v6*__uint_as_float(m6&0xffff0000u);
        ax3 += v7*__uint_as_float(m7<<16); ay3 += v7*__uint_as_float(m7&0xffff0000u);
    }
    for (; i < e; i++) {
        int2 p = packed[i];
        unsigned m = *(const unsigned*)(embb + ((size_t)p.x << 7) + l2);
        float v = __int_as_float(p.y);
        ax0 += v*__uint_as_float(m<<16); ay0 += v*__uint_as_float(m&0xffff0000u);
    }
    *(float2*)(h + ((size_t)r << 7) + l2) =
        make_float2((ax0+ax1)+(ax2+ax3), (ay0+ay1)+(ay2+ay3));
}

// ============ launch ============
extern "C" void kernel_launch(void* const* d_in, const int* in_sizes, int n_in,
                              void* d_out, int out_size, void* d_ws, size_t ws_size,
                              hipStream_t stream)
{
    const float* feat  = (const float*)d_in[0];
    const int*   srows = (const int*)  d_in[1];
    const int*   scols = (const int*)  d_in[2];
    const float* svals = (const float*)d_in[3];
    const float* Wf0   = (const float*)d_in[4];
    const float* bf0   = (const float*)d_in[5];
    const float* Wf1   = (const float*)d_in[6];
    const float* bf1   = (const float*)d_in[7];
    const float* Wg    = (const float*)d_in[8];
    const float* Wemb  = (const float*)d_in[9];
    const float* bemb  = (const float*)d_in[10];
    const float* Wl    = (const float*)d_in[11];
    const float* bl    = (const float*)d_in[12];
    const float* Wr    = (const float*)d_in[13];
    const float* br    = (const float*)d_in[14];

    const int M = in_sizes[0] / 512;   // 100000 nodes
    const int E = in_sizes[1];         // 3200000 edges

    float* out  = (float*)d_out;
    float* R0 = out;                        // embO final
    float* R1 = out + (size_t)M * 128;      // lftO final
    float* R2 = out + (size_t)M * 256;      // rgtO final

    // ---- ws layout (~78.2 MB, same footprint as R5) ----
    float* ws = (float*)d_ws;
    float* x  = ws;                                        // [M,128] f32; becomes acc in-place
    int*   ip = (int*)(ws + (size_t)M * 128);
    int*   rowptr  = ip;                                   // M+1
    int*   cnt     = ip + (((size_t)M + 4) & ~(size_t)3);  // M
    int2*  packed  = (int2*)(cnt + M);                     // E
    int*   tilesum = (int*)(packed + E);                   // 64
    unsigned short* Wt0   = (unsigned short*)(tilesum + 64);   // [256][512]
    unsigned short* Wt1   = Wt0 + 256 * 512;                   // [128][256]
    unsigned short* Wg0t  = Wt1 + 128 * 256;                   // 7x [128][128]
    unsigned short* Wg1t  = Wg0t + 16384;
    unsigned short* Wembt = Wg1t + 16384;
    unsigned short* Wl0t  = Wembt + 16384;
    unsigned short* Wl1t  = Wl0t + 16384;
    unsigned short* Wr0t  = Wl1t + 16384;
    unsigned short* Wr1t  = Wr0t + 16384;

    // ---- d_out scratch timeline (audited; rgt tower before lft, emb last) ----
    unsigned short* feat_bf = (unsigned short*)R0;               // [M,512] = R0+R1, dead after s1
    unsigned short* x1_bf   = (unsigned short*)R2;               // [M,256] = R2,   dead after s2
    unsigned short* x_bf    = (unsigned short*)R0;               // [M,128] = R0 1st half, dead after spmm3
    unsigned short* n0_bf   = (unsigned short*)R0 + (size_t)M*128; // R0 2nd half, dead after spmm5
    unsigned short* n1_bf   = n0_bf;                             // R0 2nd half, alive s6..s8
    unsigned short* lft0_bf = (unsigned short*)R0;               // R0 1st half, alive s8..s9
    unsigned short* rgt0_bf = (unsigned short*)R1;               // R1 1st half, alive s10..s11
    float* h   = R1;                                             // spmm acc, dead after s6
    float* acc = x;                                              // gnn_acc aliases x (in-place add)

    dim3 blk(256);
    const int gm128 = (M + 127) / 128;                 // 782
    const int ge    = (E + 255) / 256;
    const int numTiles = (M + SCAN_TILE - 1) / SCAN_TILE;

    // weight converts
    wconv<<<(512*256 + 255)/256, blk, 0, stream>>>(Wf0, Wt0, 512, 256);
    wconv<<<(256*128 + 255)/256, blk, 0, stream>>>(Wf1, Wt1, 256, 128);
    wconv<<<64, blk, 0, stream>>>(Wg,          Wg0t,  128, 128);
    wconv<<<64, blk, 0, stream>>>(Wg + 16384,  Wg1t,  128, 128);
    wconv<<<64, blk, 0, stream>>>(Wemb,        Wembt, 128, 128);
    wconv<<<64, blk, 0, stream>>>(Wl,          Wl0t,  128, 128);
    wconv<<<64, blk, 0, stream>>>(Wl + 16384,  Wl1t,  128, 128);
    wconv<<<64, blk, 0, stream>>>(Wr,          Wr0t,  128, 128);
    wconv<<<64, blk, 0, stream>>>(Wr + 16384,  Wr1t,  128, 128);

    // feat -> bf16 (into R0+R1)
    f32_to_bf16<<<(int)(((long)M * 64 + 255) / 256), blk, 0, stream>>>(feat, feat_bf, (long)M * 64);

    // CSR build
    hipMemsetAsync(cnt, 0, (size_t)M * 4, stream);
    hist_k<<<ge, blk, 0, stream>>>(srows, cnt, E);
    scan_phaseA<<<numTiles, blk, 0, stream>>>(cnt, tilesum, M);
    scan_phaseB<<<1, 64, 0, stream>>>(tilesum, rowptr, numTiles, M);
    scan_phaseC<<<numTiles, blk, 0, stream>>>(cnt, tilesum, rowptr, M);
    hipMemsetAsync(cnt, 0, (size_t)M * 4, stream);
    reorder_k<<<ge, blk, 0, stream>>>(srows, scols, svals, rowptr, cnt, packed, E);

    // s1: x1_bf = tanh(feat @ Wf0 + bf0)            [bf16 out only]
    mfma_big<false,true,true><<<dim3(gm128,2),blk,0,stream>>>(feat_bf, Wt0, bf0, nullptr, x1_bf, M, 512, 256);
    // s2: x = tanh(x1 @ Wf1 + bf1)  (f32 + bf16)
    mfma_big<true,true,true><<<dim3(gm128,1),blk,0,stream>>>(x1_bf, Wt1, bf1, x, x_bf, M, 256, 128);
    // spmm3: h = S @ x
    spmm_csr<<<(M + 3) / 4, blk, 0, stream>>>(rowptr, packed, x_bf, h, M);
    // s4: n0 = l2norm(tanh(h @ Wg0)) -> n0_bf; acc = x + n0  (in-place on x)
    mfma_ep<false,true,true,false,true,false,true,false><<<gm128,blk,0,stream>>>(
        h, Wg0t, nullptr, nullptr, x, acc, nullptr, n0_bf, M);
    // spmm5: h = S @ n0
    spmm_csr<<<(M + 3) / 4, blk, 0, stream>>>(rowptr, packed, n0_bf, h, M);
    // s6: n1 = l2norm(tanh(h @ Wg1)) -> n1_bf; acc += n1
    mfma_ep<false,true,true,false,true,false,true,false><<<gm128,blk,0,stream>>>(
        h, Wg1t, nullptr, nullptr, acc, acc, nullptr, n1_bf, M);
    // s10: rgt0 = tanh(n1 @ Wr0 + br0) + n1 -> rgt0_bf
    mfma_ep<true,true,false,true,false,false,true,true><<<gm128,blk,0,stream>>>(
        n1_bf, Wr0t, br, n1_bf, nullptr, nullptr, nullptr, rgt0_bf, M);
    // s11: rgt = tanh(rgt0 @ Wr1 + br1) -> rgtO (final)
    mfma_ep<true,true,false,false,false,true,false,true><<<gm128,blk,0,stream>>>(
        rgt0_bf, Wr1t, br + 128, nullptr, nullptr, nullptr, R2, nullptr, M);
    // s8: lft0 = tanh(n1 @ Wl0 + bl0) + n1 -> lft0_bf
    mfma_ep<true,true,false,true,false,false,true,true><<<gm128,blk,0,stream>>>(
        n1_bf, Wl0t, bl, n1_bf, nullptr, nullptr, nullptr, lft0_bf, M);
    // s9: lft = tanh(lft0 @ Wl1 + bl1) -> lftO (final)
    mfma_ep<true,true,false,false,false,true,false,true><<<gm128,blk,0,stream>>>(
        lft0_bf, Wl1t, bl + 128, nullptr, nullptr, nullptr, R1, nullptr, M);
    // s7: emb = l2norm(acc @ Wemb + bemb) -> embO (final, last so R0 scratch is free)
    mfma_ep<false,false,true,false,false,true,false,true><<<gm128,blk,0,stream>>>(
        acc, Wembt, bemb, nullptr, nullptr, nullptr, R0, nullptr, M);
}